// Round 4
// baseline (179.028 us; speedup 1.0000x reference)
//
#include <hip/hip_runtime.h>

typedef _Float16 half8  __attribute__((ext_vector_type(8)));
typedef _Float16 half4v __attribute__((ext_vector_type(4)));
typedef float    floatx4 __attribute__((ext_vector_type(4)));

static constexpr int BR      = 256;  // batch rows per block
static constexpr int FG      = 16;   // features per block (one 64B line of x/y)
static constexpr int XP      = 17;   // padded LDS row stride (floats)
static constexpr int THREADS = 256;  // 4 waves
#define NEG_SLOPE 0.05f

// fp32 -> fp16 pre-conversion of W2 (262144 elements) into workspace.
__global__ __launch_bounds__(256)
void w2_half_kernel(const float* __restrict__ W2, _Float16* __restrict__ W2h) {
    int i = (blockIdx.x * 256 + threadIdx.x) * 4;
    floatx4 v = *reinterpret_cast<const floatx4*>(W2 + i);
    half4v h;
    h[0] = (_Float16)v[0]; h[1] = (_Float16)v[1];
    h[2] = (_Float16)v[2]; h[3] = (_Float16)v[3];
    *reinterpret_cast<half4v*>(W2h + i) = h;
}

__global__ __launch_bounds__(THREADS, 3)
void mft_kernel(const float* __restrict__ x,
                const float* __restrict__ W1,
                const float* __restrict__ b1,
                const _Float16* __restrict__ W2h,
                const float* __restrict__ b2,
                const float* __restrict__ W3,
                const float* __restrict__ b3,
                float* __restrict__ y) {
    __shared__ float xl[BR * XP];
    __shared__ float yl[BR * XP];

    const int tid   = threadIdx.x;
    const int fg    = blockIdx.x & 3;   // feature group: f in [fg*16, fg*16+16)
    const int chunk = blockIdx.x >> 2;  // row chunk: rows [chunk*256, +256)
    const int gbase = chunk * (BR * 64) + fg * FG;  // elem offset of (row0, f0)

    // ---- stage x tile (256 rows x 16 feats), full 64B lines, coalesced ----
    #pragma unroll
    for (int k = 0; k < (BR * FG) / (THREADS * 4); ++k) {
        int i  = (k * THREADS + tid) * 4;  // 0..4095 step 4
        int r  = i >> 4;
        int fi = i & 15;
        floatx4 v = *reinterpret_cast<const floatx4*>(x + gbase + r * 64 + fi);
        xl[r * XP + fi + 0] = v[0];
        xl[r * XP + fi + 1] = v[1];
        xl[r * XP + fi + 2] = v[2];
        xl[r * XP + fi + 3] = v[3];
    }
    __syncthreads();

    const int lane = tid & 63;
    const int wave = tid >> 6;   // 0..3
    const int l15  = lane & 15;
    const int lg   = lane >> 4;  // 0..3

    for (int fi = 0; fi < FG; ++fi) {
        const int f = fg * FG + fi;
        const _Float16* w2f = W2h + f * 4096;

        // A fragments: A[g_row][k] ; g_row = m*16 + (lane&15), k = s*32 + (lane>>4)*8 + j
        half8 afrag[4][2];
        #pragma unroll
        for (int m = 0; m < 4; ++m)
            #pragma unroll
            for (int s = 0; s < 2; ++s)
                afrag[m][s] = *reinterpret_cast<const half8*>(
                    w2f + (m * 16 + l15) * 64 + s * 32 + lg * 8);

        // W1/b1 slices for this lane's K range (layer-1 in fp32)
        floatx4 w1a[2][2], b1a[2][2];
        #pragma unroll
        for (int s = 0; s < 2; ++s) {
            const int ko = s * 32 + lg * 8;
            w1a[s][0] = *reinterpret_cast<const floatx4*>(W1 + f * 64 + ko);
            w1a[s][1] = *reinterpret_cast<const floatx4*>(W1 + f * 64 + ko + 4);
            b1a[s][0] = *reinterpret_cast<const floatx4*>(b1 + f * 64 + ko);
            b1a[s][1] = *reinterpret_cast<const floatx4*>(b1 + f * 64 + ko + 4);
        }
        // b2 / W3 along C rows: g = m*16 + (lane>>4)*4 + q
        floatx4 b2a[4], w3a[4];
        #pragma unroll
        for (int m = 0; m < 4; ++m) {
            b2a[m] = *reinterpret_cast<const floatx4*>(b2 + f * 64 + m * 16 + lg * 4);
            w3a[m] = *reinterpret_cast<const floatx4*>(W3 + f * 64 + m * 16 + lg * 4);
        }
        const float b3v = b3[f];

        #pragma unroll
        for (int t = 0; t < 4; ++t) {
            const int r = (wave * 4 + t) * 16 + l15;  // local batch row
            const float xv = xl[r * XP + fi];

            // B fragment: h1^T[k][b_col] ; b_col = lane&15 (this lane's row)
            half8 bfrag[2];
            #pragma unroll
            for (int s = 0; s < 2; ++s)
                #pragma unroll
                for (int j = 0; j < 8; ++j) {
                    float v = fmaf(xv, w1a[s][j >> 2][j & 3], b1a[s][j >> 2][j & 3]);
                    v = fmaxf(v, NEG_SLOPE * v);   // leaky
                    bfrag[s][j] = (_Float16)v;
                }

            float yv = 0.0f;
            #pragma unroll
            for (int m = 0; m < 4; ++m) {
                floatx4 acc = b2a[m];  // fold +b2 into accumulator init
                acc = __builtin_amdgcn_mfma_f32_16x16x32_f16(afrag[m][0], bfrag[0], acc, 0, 0, 0);
                acc = __builtin_amdgcn_mfma_f32_16x16x32_f16(afrag[m][1], bfrag[1], acc, 0, 0, 0);
                #pragma unroll
                for (int q = 0; q < 4; ++q) {
                    float h2 = acc[q];
                    h2 = fmaxf(h2, NEG_SLOPE * h2);  // leaky
                    yv = fmaf(h2, w3a[m][q], yv);    // * W3, partial over g
                }
            }
            // sum partial g-groups across the 4 lane-groups
            yv += __shfl_xor(yv, 16, 64);
            yv += __shfl_xor(yv, 32, 64);
            if (lane < 16)
                yl[r * XP + fi] = yv + b3v;
        }
    }
    __syncthreads();

    // ---- write y tile out, full 64B lines, coalesced ----
    #pragma unroll
    for (int k = 0; k < (BR * FG) / (THREADS * 4); ++k) {
        int i  = (k * THREADS + tid) * 4;
        int r  = i >> 4;
        int fi = i & 15;
        floatx4 v;
        v[0] = yl[r * XP + fi + 0];
        v[1] = yl[r * XP + fi + 1];
        v[2] = yl[r * XP + fi + 2];
        v[3] = yl[r * XP + fi + 3];
        *reinterpret_cast<floatx4*>(y + gbase + r * 64 + fi) = v;
    }
}

extern "C" void kernel_launch(void* const* d_in, const int* in_sizes, int n_in,
                              void* d_out, int out_size, void* d_ws, size_t ws_size,
                              hipStream_t stream) {
    const float* x  = (const float*)d_in[0];
    const float* W1 = (const float*)d_in[1];
    const float* b1 = (const float*)d_in[2];
    const float* W2 = (const float*)d_in[3];
    const float* b2 = (const float*)d_in[4];
    const float* W3 = (const float*)d_in[5];
    const float* b3 = (const float*)d_in[6];
    float*       yo = (float*)d_out;
    _Float16*  W2h  = (_Float16*)d_ws;   // 512 KB

    w2_half_kernel<<<dim3(262144 / 1024), dim3(256), 0, stream>>>(W2, W2h);

    const int nblocks = (65536 / BR) * 4;  // 1024
    mft_kernel<<<dim3(nblocks), dim3(THREADS), 0, stream>>>(
        x, W1, b1, W2h, b2, W3, b3, yo);
}

// Round 5
// 173.752 us; speedup vs baseline: 1.0304x; 1.0304x over previous
//
#include <hip/hip_runtime.h>

typedef _Float16 half8  __attribute__((ext_vector_type(8)));
typedef _Float16 half4v __attribute__((ext_vector_type(4)));
typedef _Float16 half2v __attribute__((ext_vector_type(2)));
typedef float    floatx4 __attribute__((ext_vector_type(4)));

static constexpr int BR      = 256;  // batch rows per block
static constexpr int FG      = 16;   // features per block (one 64B line of x/y)
static constexpr int XPH     = 20;   // xl stride in halfs (40B rows: 8B-aligned, bank-clean)
static constexpr int XPF     = 17;   // yl stride in floats
static constexpr int THREADS = 256;  // 4 waves
#define NEG_SLOPE 0.05f

// fp16 pack layout in workspace
static constexpr int W2_OFF     = 0;        // 64*64*64
static constexpr int W1_OFF     = 262144;   // 64*64
static constexpr int B1_OFF     = 266240;   // 64*64
static constexpr int PACK_TOTAL = 270336;

__global__ __launch_bounds__(256)
void pack_kernel(const float* __restrict__ W2, const float* __restrict__ W1,
                 const float* __restrict__ b1, _Float16* __restrict__ out) {
    int i = (blockIdx.x * 256 + threadIdx.x) * 4;
    if (i >= PACK_TOTAL) return;
    const float* src;
    int base;
    if (i < W1_OFF)      { src = W2; base = 0; }
    else if (i < B1_OFF) { src = W1; base = W1_OFF; }
    else                 { src = b1; base = B1_OFF; }
    floatx4 v = *reinterpret_cast<const floatx4*>(src + (i - base));
    half4v h;
    h[0] = (_Float16)v[0]; h[1] = (_Float16)v[1];
    h[2] = (_Float16)v[2]; h[3] = (_Float16)v[3];
    *reinterpret_cast<half4v*>(out + i) = h;
}

__global__ __launch_bounds__(THREADS, 4)
void mft_kernel(const float* __restrict__ x,
                const _Float16* __restrict__ wpk,
                const float* __restrict__ b2,
                const float* __restrict__ W3,
                const float* __restrict__ b3,
                float* __restrict__ y) {
    __shared__ _Float16 xl[BR * XPH];
    __shared__ float    yl[BR * XPF];

    const _Float16* __restrict__ W2h = wpk + W2_OFF;
    const _Float16* __restrict__ W1h = wpk + W1_OFF;
    const _Float16* __restrict__ B1h = wpk + B1_OFF;

    const int tid   = threadIdx.x;
    const int fg    = blockIdx.x & 3;   // feature group: f in [fg*16, fg*16+16)
    const int chunk = blockIdx.x >> 2;  // row chunk: rows [chunk*256, +256)
    const int gbase = chunk * (BR * 64) + fg * FG;  // elem offset of (row0, f0)

    // ---- stage x tile (256 rows x 16 feats) as fp16, coalesced 64B lines ----
    #pragma unroll
    for (int k = 0; k < (BR * FG) / (THREADS * 4); ++k) {
        int i  = (k * THREADS + tid) * 4;  // 0..4095 step 4
        int r  = i >> 4;
        int fi = i & 15;
        floatx4 v = *reinterpret_cast<const floatx4*>(x + gbase + r * 64 + fi);
        half4v h;
        h[0] = (_Float16)v[0]; h[1] = (_Float16)v[1];
        h[2] = (_Float16)v[2]; h[3] = (_Float16)v[3];
        *reinterpret_cast<half4v*>(&xl[r * XPH + fi]) = h;
    }
    __syncthreads();

    const int lane = tid & 63;
    const int wave = tid >> 6;   // 0..3
    const int l15  = lane & 15;
    const int lg   = lane >> 4;  // 0..3

    const half2v c005 = {(_Float16)NEG_SLOPE, (_Float16)NEG_SLOPE};

    #pragma unroll 2
    for (int fi = 0; fi < FG; ++fi) {
        const int f = fg * FG + fi;
        const _Float16* w2f = W2h + f * 4096;

        // A fragments: A[g_row][k] ; g_row = m*16 + (lane&15), k = s*32 + (lane>>4)*8 + j
        half8 afrag[4][2];
        #pragma unroll
        for (int m = 0; m < 4; ++m)
            #pragma unroll
            for (int s = 0; s < 2; ++s)
                afrag[m][s] = *reinterpret_cast<const half8*>(
                    w2f + (m * 16 + l15) * 64 + s * 32 + lg * 8);

        // W1/b1 fp16 slices for this lane's K range (2 x 16B loads each)
        half8 w1c[2], b1c[2];
        #pragma unroll
        for (int s = 0; s < 2; ++s) {
            w1c[s] = *reinterpret_cast<const half8*>(W1h + f * 64 + s * 32 + lg * 8);
            b1c[s] = *reinterpret_cast<const half8*>(B1h + f * 64 + s * 32 + lg * 8);
        }
        // b2 / W3 along C rows: g = m*16 + (lane>>4)*4 + q  (fp32)
        floatx4 b2a[4], w3a[4];
        #pragma unroll
        for (int m = 0; m < 4; ++m) {
            b2a[m] = *reinterpret_cast<const floatx4*>(b2 + f * 64 + m * 16 + lg * 4);
            w3a[m] = *reinterpret_cast<const floatx4*>(W3 + f * 64 + m * 16 + lg * 4);
        }
        const float b3v = b3[f];

        #pragma unroll
        for (int t = 0; t < 4; ++t) {
            const int r = (wave * 4 + t) * 16 + l15;  // local batch row
            const _Float16 xh = xl[r * XPH + fi];
            const half2v x2 = {xh, xh};

            // B fragment: h1^T[k][b_col] via packed fp16 fma + leaky
            half8 bf0, bf1;
            #pragma unroll
            for (int p = 0; p < 4; ++p) {
                half2v w0 = {w1c[0][2 * p], w1c[0][2 * p + 1]};
                half2v c0 = {b1c[0][2 * p], b1c[0][2 * p + 1]};
                half2v h0 = x2 * w0 + c0;
                half2v r0 = __builtin_elementwise_max(h0, h0 * c005);
                bf0[2 * p] = r0[0]; bf0[2 * p + 1] = r0[1];

                half2v w1_ = {w1c[1][2 * p], w1c[1][2 * p + 1]};
                half2v c1 = {b1c[1][2 * p], b1c[1][2 * p + 1]};
                half2v h1 = x2 * w1_ + c1;
                half2v r1 = __builtin_elementwise_max(h1, h1 * c005);
                bf1[2 * p] = r1[0]; bf1[2 * p + 1] = r1[1];
            }

            float yv = 0.0f;
            #pragma unroll
            for (int m = 0; m < 4; ++m) {
                floatx4 acc = b2a[m];  // fold +b2 into accumulator init
                acc = __builtin_amdgcn_mfma_f32_16x16x32_f16(afrag[m][0], bf0, acc, 0, 0, 0);
                acc = __builtin_amdgcn_mfma_f32_16x16x32_f16(afrag[m][1], bf1, acc, 0, 0, 0);
                #pragma unroll
                for (int q = 0; q < 4; ++q) {
                    float h2 = acc[q];
                    h2 = fmaxf(h2, NEG_SLOPE * h2);  // leaky
                    yv = fmaf(h2, w3a[m][q], yv);    // * W3, partial over g
                }
            }
            // sum partial g-groups across the 4 lane-groups
            yv += __shfl_xor(yv, 16, 64);
            yv += __shfl_xor(yv, 32, 64);
            if (lane < 16)
                yl[r * XPF + fi] = yv + b3v;
        }
    }
    __syncthreads();

    // ---- write y tile out, full 64B lines, coalesced ----
    #pragma unroll
    for (int k = 0; k < (BR * FG) / (THREADS * 4); ++k) {
        int i  = (k * THREADS + tid) * 4;
        int r  = i >> 4;
        int fi = i & 15;
        floatx4 v;
        v[0] = yl[r * XPF + fi + 0];
        v[1] = yl[r * XPF + fi + 1];
        v[2] = yl[r * XPF + fi + 2];
        v[3] = yl[r * XPF + fi + 3];
        *reinterpret_cast<floatx4*>(y + gbase + r * 64 + fi) = v;
    }
}

extern "C" void kernel_launch(void* const* d_in, const int* in_sizes, int n_in,
                              void* d_out, int out_size, void* d_ws, size_t ws_size,
                              hipStream_t stream) {
    const float* x  = (const float*)d_in[0];
    const float* W1 = (const float*)d_in[1];
    const float* b1 = (const float*)d_in[2];
    const float* W2 = (const float*)d_in[3];
    const float* b2 = (const float*)d_in[4];
    const float* W3 = (const float*)d_in[5];
    const float* b3 = (const float*)d_in[6];
    float*       yo = (float*)d_out;
    _Float16*   wpk = (_Float16*)d_ws;   // 528 KB packed fp16 weights

    pack_kernel<<<dim3(PACK_TOTAL / 1024), dim3(256), 0, stream>>>(W2, W1, b1, wpk);

    const int nblocks = (65536 / BR) * 4;  // 1024
    mft_kernel<<<dim3(nblocks), dim3(THREADS), 0, stream>>>(
        x, wpk, b2, W3, b3, yo);
}